// Round 2
// baseline (699.278 us; speedup 1.0000x reference)
//
#include <hip/hip_runtime.h>
#include <hip/hip_bf16.h>
#include <math.h>

typedef __attribute__((ext_vector_type(8))) short bf16x8;
typedef __attribute__((ext_vector_type(4))) float f32x4;
typedef unsigned short ushort_t;

__device__ inline ushort_t f2bf(float f){
  union{float f; unsigned v;} x; x.f = f;
  unsigned r = x.v + 0x7fff + ((x.v>>16)&1);
  return (ushort_t)(r>>16);
}

// ---------------- fp32 -> bf16 convert ----------------
__global__ __launch_bounds__(256) void cvt_kernel(const float* __restrict__ in, ushort_t* __restrict__ out){
  int i = (blockIdx.x*256 + threadIdx.x)*4;
  float4 v = *(const float4*)(in+i);
  ushort4 o; o.x=f2bf(v.x); o.y=f2bf(v.y); o.z=f2bf(v.z); o.w=f2bf(v.w);
  *(ushort4*)(out+i) = o;
}

// ---------------- LayerNorm (row of 768), fp32 in -> bf16 out ----------------
__global__ __launch_bounds__(256) void ln_kernel(const float* __restrict__ x, const float* __restrict__ w,
                                                 const float* __restrict__ b, ushort_t* __restrict__ out){
  int row = blockIdx.x;
  const float* xr = x + (size_t)row*768;
  int t = threadIdx.x;
  float v0=xr[t], v1=xr[t+256], v2=xr[t+512];
  float s = v0+v1+v2;
  float s2 = v0*v0+v1*v1+v2*v2;
  for(int m=1;m<64;m<<=1){ s += __shfl_xor(s,m,64); s2 += __shfl_xor(s2,m,64); }
  __shared__ float ls[4], ls2[4];
  int wid = t>>6;
  if((t&63)==0){ ls[wid]=s; ls2[wid]=s2; }
  __syncthreads();
  s = ls[0]+ls[1]+ls[2]+ls[3];
  s2 = ls2[0]+ls2[1]+ls2[2]+ls2[3];
  float mu = s*(1.f/768.f);
  float var = s2*(1.f/768.f) - mu*mu;
  float rs = rsqrtf(var + 1e-5f);
  ushort_t* orow = out + (size_t)row*768;
  orow[t]     = f2bf((v0-mu)*rs*w[t]    +b[t]);
  orow[t+256] = f2bf((v1-mu)*rs*w[t+256]+b[t+256]);
  orow[t+512] = f2bf((v2-mu)*rs*w[t+512]+b[t+512]);
}

// ---------------- GEMM: C[m][n] = sum_k A[m][k]*BT[n][k] + bias[n] (+epilogue) ----------------
// EPI 0: qkv scatter to [3][B*H][N][64] bf16
// EPI 1: += resid, fp32 out
// EPI 2: exact gelu, bf16 out
template<int EPI>
__global__ __launch_bounds__(256)
void gemm_bt(const ushort_t* __restrict__ A, const ushort_t* __restrict__ BT,
             const float* __restrict__ bias, const float* __restrict__ resid,
             void* __restrict__ out, int K, int Nout)
{
  __shared__ ushort_t Asm[128*32];
  __shared__ ushort_t Bsm[128*32];
  const int bm0 = blockIdx.y*128;
  const int bn0 = blockIdx.x*128;
  const int tid = threadIdx.x;
  const int lane = tid & 63;
  const int wid = tid >> 6;
  const int wr = wid >> 1, wc = wid & 1;
  const int fq = lane>>4, fr = lane&15;

  f32x4 acc[4][4];
  for(int m=0;m<4;m++) for(int n=0;n<4;n++) acc[m][n] = (f32x4){0.f,0.f,0.f,0.f};

  for(int k0=0; k0<K; k0+=32){
    for(int j=0;j<2;j++){
      int e = (wid*2+j)*512 + lane*8;
      int r = e>>5, c = e&31;
      const ushort_t* ga = A  + (size_t)(bm0+r)*K + k0 + c;
      const ushort_t* gb = BT + (size_t)(bn0+r)*K + k0 + c;
      __builtin_amdgcn_global_load_lds((const __attribute__((address_space(1))) void*)ga,
          (__attribute__((address_space(3))) void*)(Asm + (wid*2+j)*512), 16, 0, 0);
      __builtin_amdgcn_global_load_lds((const __attribute__((address_space(1))) void*)gb,
          (__attribute__((address_space(3))) void*)(Bsm + (wid*2+j)*512), 16, 0, 0);
    }
    __syncthreads();
    bf16x8 af[4], bfr[4];
    for(int m=0;m<4;m++)
      af[m] = *(const bf16x8*)(Asm + (wr*64 + m*16 + fr)*32 + fq*8);
    for(int n=0;n<4;n++)
      bfr[n] = *(const bf16x8*)(Bsm + (wc*64 + n*16 + fr)*32 + fq*8);
    for(int m=0;m<4;m++)
      for(int n=0;n<4;n++)
        acc[m][n] = __builtin_amdgcn_mfma_f32_16x16x32_bf16(af[m], bfr[n], acc[m][n], 0,0,0);
    __syncthreads();
  }

  for(int m=0;m<4;m++){
    int row0 = bm0 + wr*64 + m*16 + fq*4;
    for(int n=0;n<4;n++){
      int col = bn0 + wc*64 + n*16 + fr;
      float bv = bias[col];
      for(int j=0;j<4;j++){
        int r = row0 + j;
        float v = acc[m][n][j] + bv;
        if constexpr(EPI==0){
          int which = col>=1536 ? 2 : (col>=768 ? 1 : 0);
          int rem = col - which*768;
          int hh = rem>>6, dh = rem&63;
          int bb = r>>10, np = r&1023;
          ((ushort_t*)out)[(((size_t)(which*96 + bb*12 + hh)*1024 + np)<<6) + dh] = f2bf(v);
        } else if constexpr(EPI==1){
          v += resid[(size_t)r*768 + col];
          ((float*)out)[(size_t)r*768 + col] = v;
        } else {
          float g = 0.5f*v*(1.0f + erff(v*0.70710678118f));
          ((ushort_t*)out)[(size_t)r*(size_t)Nout + col] = f2bf(g);
        }
      }
    }
  }
}

// ---------------- Flash attention: per (b*h, qtile) ----------------
// qkv layout: [3][96][1024][64] bf16.  out: [B][N][768] bf16 (head-interleaved)
__global__ __launch_bounds__(256)
void attn_kernel(const ushort_t* __restrict__ qkv, ushort_t* __restrict__ outp)
{
  __shared__ ushort_t Ksm[64*72];
  __shared__ ushort_t Vt[64*72];
  __shared__ ushort_t Psm[4][16*72];
  const int bh = blockIdx.x;
  const int q0 = blockIdx.y*64;
  const int tid = threadIdx.x, lane = tid&63, wid = tid>>6;
  const int fq = lane>>4, fr = lane&15;
  const ushort_t* Qb = qkv + ((size_t)bh*1024)*64;
  const ushort_t* Kb = qkv + ((size_t)(96 + bh)*1024)*64;
  const ushort_t* Vb = qkv + ((size_t)(192 + bh)*1024)*64;

  bf16x8 qf[2];
  {
    int qr = q0 + wid*16 + fr;
    qf[0] = *(const bf16x8*)(Qb + (size_t)qr*64 +      fq*8);
    qf[1] = *(const bf16x8*)(Qb + (size_t)qr*64 + 32 + fq*8);
  }
  f32x4 o[4];
  for(int dt=0;dt<4;dt++) o[dt] = (f32x4){0.f,0.f,0.f,0.f};
  float mrun[4], lrun[4];
  for(int j=0;j<4;j++){ mrun[j] = -1e30f; lrun[j]=0.f; }

  for(int kt=0; kt<16; kt++){
    int kv0 = kt*64;
    for(int p=0;p<2;p++){
      int e = (p*256 + tid)*8;
      int r = e>>6, c = e&63;
      *(bf16x8*)(Ksm + r*72 + c) = *(const bf16x8*)(Kb + (size_t)(kv0+r)*64 + c);
      bf16x8 v = *(const bf16x8*)(Vb + (size_t)(kv0+r)*64 + c);
      for(int j=0;j<8;j++) Vt[(c+j)*72 + r] = (ushort_t)v[j];
    }
    __syncthreads();

    f32x4 s[4];
    for(int ct=0;ct<4;ct++){
      bf16x8 kf0 = *(const bf16x8*)(Ksm + (ct*16 + fr)*72 +      fq*8);
      bf16x8 kf1 = *(const bf16x8*)(Ksm + (ct*16 + fr)*72 + 32 + fq*8);
      f32x4 z = (f32x4){0.f,0.f,0.f,0.f};
      z = __builtin_amdgcn_mfma_f32_16x16x32_bf16(qf[0], kf0, z, 0,0,0);
      z = __builtin_amdgcn_mfma_f32_16x16x32_bf16(qf[1], kf1, z, 0,0,0);
      s[ct] = z;
    }
    const float scale = 0.125f;
    float alpha[4];
    for(int j=0;j<4;j++){
      float v = fmaxf(fmaxf(s[0][j],s[1][j]),fmaxf(s[2][j],s[3][j]));
      for(int m=1;m<16;m<<=1) v = fmaxf(v, __shfl_xor(v,m,64));
      float mnew = fmaxf(mrun[j], v*scale);
      alpha[j] = __expf(mrun[j]-mnew);
      mrun[j] = mnew;
    }
    float rs[4] = {0.f,0.f,0.f,0.f};
    for(int ct=0;ct<4;ct++){
      float p[4];
      for(int j=0;j<4;j++){
        p[j] = __expf(s[ct][j]*scale - mrun[j]);
        rs[j] += p[j];
      }
      for(int j=0;j<4;j++)
        Psm[wid][(fq*4 + j)*72 + ct*16 + fr] = f2bf(p[j]);
    }
    for(int j=0;j<4;j++){
      float v = rs[j];
      for(int m=1;m<16;m<<=1) v += __shfl_xor(v,m,64);
      lrun[j] = lrun[j]*alpha[j] + v;
    }
    for(int dt=0;dt<4;dt++) for(int j=0;j<4;j++) o[dt][j]*=alpha[j];

    bf16x8 pf[2];
    pf[0] = *(const bf16x8*)(&Psm[wid][fr*72 +      fq*8]);
    pf[1] = *(const bf16x8*)(&Psm[wid][fr*72 + 32 + fq*8]);
    for(int dt=0;dt<4;dt++){
      for(int kc=0;kc<2;kc++){
        bf16x8 vf = *(const bf16x8*)(Vt + (dt*16 + fr)*72 + kc*32 + fq*8);
        o[dt] = __builtin_amdgcn_mfma_f32_16x16x32_bf16(pf[kc], vf, o[dt], 0,0,0);
      }
    }
    __syncthreads();
  }

  int b = bh/12, h = bh%12;
  for(int dt=0;dt<4;dt++){
    for(int j=0;j<4;j++){
      int qr = q0 + wid*16 + fq*4 + j;
      float v = o[dt][j] / lrun[j];
      outp[(size_t)(b*1024 + qr)*768 + h*64 + dt*16 + fr] = f2bf(v);
    }
  }
}

extern "C" void kernel_launch(void* const* d_in, const int* in_sizes, int n_in,
                              void* d_out, int out_size, void* d_ws, size_t ws_size,
                              hipStream_t stream)
{
  const float* x     = (const float*)d_in[0];
  const float* ln1w  = (const float*)d_in[1];
  const float* ln1b  = (const float*)d_in[2];
  const float* qkvw  = (const float*)d_in[3];
  const float* qkvb  = (const float*)d_in[4];
  const float* projw = (const float*)d_in[5];
  const float* projb = (const float*)d_in[6];
  const float* ln2w  = (const float*)d_in[7];
  const float* ln2b  = (const float*)d_in[8];
  const float* fc1w  = (const float*)d_in[9];
  const float* fc1b  = (const float*)d_in[10];
  const float* fc2w  = (const float*)d_in[11];
  const float* fc2b  = (const float*)d_in[12];

  char* ws = (char*)d_ws;
  size_t off = 0;
  auto alloc = [&](size_t bytes){ char* p = ws + off; off += (bytes + 255) & ~255ULL; return p; };
  ushort_t* wq = (ushort_t*)alloc((size_t)2304*768*2);
  ushort_t* wp = (ushort_t*)alloc((size_t)768*768*2);
  ushort_t* w1 = (ushort_t*)alloc((size_t)3072*768*2);
  ushort_t* w2 = (ushort_t*)alloc((size_t)768*3072*2);
  ushort_t* lnbuf  = (ushort_t*)alloc((size_t)8192*768*2);
  ushort_t* qkvbuf = (ushort_t*)alloc((size_t)3*96*1024*64*2);   // 37748736 B (mult of 256)
  ushort_t* attno  = (ushort_t*)alloc((size_t)8192*768*2);       // contiguous after qkvbuf
  ushort_t* hbuf   = qkvbuf;   // overlay: fc1 output [8192][3072] reuses qkvbuf+attno (both dead)
  float* x1 = (float*)d_out;   // x1 lives in d_out (fp32 [8192][768]); final GEMM reads+writes in place

  // 1) weights -> bf16
  cvt_kernel<<<2304*768/1024, 256, 0, stream>>>(qkvw, wq);
  cvt_kernel<<< 768*768/1024, 256, 0, stream>>>(projw, wp);
  cvt_kernel<<<3072*768/1024, 256, 0, stream>>>(fc1w, w1);
  cvt_kernel<<<768*3072/1024, 256, 0, stream>>>(fc2w, w2);
  // 2) LN1
  ln_kernel<<<8192, 256, 0, stream>>>(x, ln1w, ln1b, lnbuf);
  // 3) QKV GEMM (scatter to heads)
  gemm_bt<0><<<dim3(18,64), 256, 0, stream>>>(lnbuf, wq, qkvb, nullptr, qkvbuf, 768, 2304);
  // 4) attention
  attn_kernel<<<dim3(96,16), 256, 0, stream>>>(qkvbuf, attno);
  // 5) proj + residual -> x1 (in d_out)
  gemm_bt<1><<<dim3(6,64), 256, 0, stream>>>(attno, wp, projb, x, x1, 768, 768);
  // 6) LN2
  ln_kernel<<<8192, 256, 0, stream>>>(x1, ln2w, ln2b, lnbuf);
  // 7) fc1 + gelu
  gemm_bt<2><<<dim3(24,64), 256, 0, stream>>>(lnbuf, w1, fc1b, nullptr, hbuf, 768, 3072);
  // 8) fc2 + residual (in-place on d_out)
  gemm_bt<1><<<dim3(6,64), 256, 0, stream>>>(hbuf, w2, fc2b, x1, (float*)d_out, 3072, 768);
}